// Round 7
// baseline (3461.917 us; speedup 1.0000x reference)
//
#include <hip/hip_runtime.h>
#include <stdint.h>

typedef _Float16 f16x8 __attribute__((ext_vector_type(8)));
typedef _Float16 f16x4 __attribute__((ext_vector_type(4)));
typedef float    f32x4 __attribute__((ext_vector_type(4)));

#define T_LEN 512
#define RLX   __ATOMIC_RELAXED
#define AGT   __HIP_MEMORY_SCOPE_AGENT

union U64x2 { unsigned long long u[2]; f16x8 v; };
union PK4   { _Float16 h[4]; unsigned long long q; };

// ---------------------------------------------------------------------------
// async global->LDS (16B/lane). LDS dest = wave-uniform base + lane*16.
// GLOBAL SOURCE IS PER-LANE: caller passes this lane's address.
// ---------------------------------------------------------------------------
__device__ __forceinline__ void gload_lds16(const void* gsrc, void* ldsdst) {
    auto g = (const __attribute__((address_space(1))) void*)(reinterpret_cast<uintptr_t>(gsrc));
    auto s = (__attribute__((address_space(3))) void*)(reinterpret_cast<uintptr_t>(ldsdst));
    __builtin_amdgcn_global_load_lds(g, s, 16, 0, 0);
}
__device__ __forceinline__ void wait_vm0() {
    asm volatile("s_waitcnt vmcnt(0)" ::: "memory");
    __builtin_amdgcn_sched_barrier(0);
}

// ---------------------------------------------------------------------------
// prep: f16 weights (Wci=[W_iz;W_in], Whc=[W_hz;W_hn]), bc=b_i+b_h,
// zero hbuf, zero flags. Must run every launch (graph replays).
// ---------------------------------------------------------------------------
__global__ __launch_bounds__(256) void prep_misc(
    const float* __restrict__ W_iz, const float* __restrict__ W_in,
    const float* __restrict__ W_hz, const float* __restrict__ W_hn,
    const float* __restrict__ b_iz, const float* __restrict__ b_in,
    const float* __restrict__ b_hz, const float* __restrict__ b_hn,
    _Float16* __restrict__ Wci, _Float16* __restrict__ Whc,
    float* __restrict__ bc, _Float16* __restrict__ hbuf, int* __restrict__ flags)
{
    const int tid = blockIdx.x * 256 + threadIdx.x;
    if (tid < 131072) {                      // 2 * 1024*512/8 weight vec units
        const bool is_h = tid >= 65536;
        const int u = tid & 65535;
        const int e = u * 8;
        const int row = e >> 9;
        const int k = e & 511;
        const float* s;
        if (!is_h) s = (row < 512) ? (W_iz + (size_t)row * 512 + k)
                                   : (W_in + (size_t)(row - 512) * 512 + k);
        else       s = (row < 512) ? (W_hz + (size_t)row * 512 + k)
                                   : (W_hn + (size_t)(row - 512) * 512 + k);
        f32x4 a = *(const f32x4*)s;
        f32x4 b = *(const f32x4*)(s + 4);
        f16x8 o;
        o[0] = (_Float16)a[0]; o[1] = (_Float16)a[1];
        o[2] = (_Float16)a[2]; o[3] = (_Float16)a[3];
        o[4] = (_Float16)b[0]; o[5] = (_Float16)b[1];
        o[6] = (_Float16)b[2]; o[7] = (_Float16)b[3];
        _Float16* d = is_h ? Whc : Wci;
        *(f16x8*)(d + e) = o;
    } else if (tid < 132096) {               // 1024 combined biases
        const int j2 = tid - 131072;
        bc[j2] = (j2 < 512) ? (b_iz[j2] + b_hz[j2]) : (b_in[j2 - 512] + b_hn[j2 - 512]);
    } else if (tid < 148480) {               // zero hbuf: 131072 f16 / 8
        const int u = tid - 132096;
        f16x8 z = { (_Float16)0, (_Float16)0, (_Float16)0, (_Float16)0,
                    (_Float16)0, (_Float16)0, (_Float16)0, (_Float16)0 };
        *(f16x8*)(hbuf + (size_t)u * 8) = z;
    } else if (tid < 148544) {               // 64 flags
        flags[tid - 148480] = 0;
    }
}

// ---------------------------------------------------------------------------
// Phase 1: input projections -> 4KB records in d_out:
//   record (t, sw) at byte (t*64+sw)*4096, sw = (b>>4)*8 + (j>>6):
//   [z: 2KB][n: 2KB]; within gate region f16 idx = ((j>>4)&3)*256 + l*4
//   where l = ((j>>2)&3)*16 + (b&15); each f16x4 = quad j..j+4 for one b.
// GEMM core unchanged from round 4/6 (verified); epilogue rewritten.
// ---------------------------------------------------------------------------
__global__ __launch_bounds__(256) void gemm_proj(
    const float* __restrict__ A,      // seq [65536][512] f32 (row = t*128+b)
    const _Float16* __restrict__ Bw,  // Wci [1024][512] f16
    const float* __restrict__ bc,     // [1024] f32
    _Float16* Co)                     // records (= d_out as f16)
{
    __shared__ _Float16 As[128 * 40];   // padded stride 40 f16
    __shared__ _Float16 Bs[128 * 32];   // linear (global_load_lds target)

    const int mt = blockIdx.x;          // = t
    const int nt = blockIdx.y;          // 0..7 (0-3: z gate, 4-7: n gate)
    const int m0 = mt * 128, n0 = nt * 128;
    const int tid = threadIdx.x;
    const int w = tid >> 6, l = tid & 63;
    const int wr = w >> 1, wc = w & 1;
    const int lrow = l & 15, lk = l >> 4;

    f32x4 acc[4][4] = {};

    const int arow = tid >> 1;
    const int acol = (tid & 1) * 16;

    for (int kt = 0; kt < 16; ++kt) {
        const int k0 = kt * 32;
        if (kt) __syncthreads();
        const float* as = A + (size_t)(m0 + arow) * 512 + k0 + acol;
        f32x4 a0 = *(const f32x4*)as;
        f32x4 a1 = *(const f32x4*)(as + 4);
        f32x4 a2 = *(const f32x4*)(as + 8);
        f32x4 a3 = *(const f32x4*)(as + 12);
        f16x8 h0, h1;
#pragma unroll
        for (int e = 0; e < 4; ++e) {
            h0[e] = (_Float16)a0[e]; h0[4 + e] = (_Float16)a1[e];
            h1[e] = (_Float16)a2[e]; h1[4 + e] = (_Float16)a3[e];
        }
        *(f16x8*)&As[arow * 40 + acol] = h0;
        *(f16x8*)&As[arow * 40 + acol + 8] = h1;
#pragma unroll
        for (int i = 0; i < 2; ++i) {
            const int chunk = w * 2 + i;
            const _Float16* gsrc =
                Bw + (size_t)(n0 + chunk * 16 + (l >> 2)) * 512 + k0 + (l & 3) * 8;
            gload_lds16(gsrc, &Bs[chunk * 512]);
        }
        __syncthreads();
        f16x8 af[4], bf[4];
#pragma unroll
        for (int i = 0; i < 4; ++i) {
            af[i] = *(const f16x8*)&As[(wr * 64 + i * 16 + lrow) * 40 + lk * 8];
            bf[i] = *(const f16x8*)&Bs[(wc * 64 + i * 16 + lrow) * 32 + lk * 8];
        }
#pragma unroll
        for (int mi = 0; mi < 4; ++mi)
#pragma unroll
            for (int ni = 0; ni < 4; ++ni)
                acc[mi][ni] = __builtin_amdgcn_mfma_f32_16x16x32_f16(
                    bf[ni], af[mi], acc[mi][ni], 0, 0, 0);
    }
    // epilogue: bias + cvt f16 + record store (full-density 8B quads)
    const int gate = nt >> 2;
#pragma unroll
    for (int mi = 0; mi < 4; ++mi) {
        const int sw = (wr * 4 + mi) * 8 + (nt & 3) * 2 + wc;
        _Float16* rec = Co + ((size_t)mt * 64 + sw) * 2048 + gate * 1024 + l * 4;
#pragma unroll
        for (int p = 0; p < 2; ++p) {
            const int j2q0 = n0 + wc * 64 + p * 32 + 4 * lk;
            const f32x4 b0 = *(const f32x4*)&bc[j2q0];
            const f32x4 b1 = *(const f32x4*)&bc[j2q0 + 16];
            f16x4 q0, q1;
#pragma unroll
            for (int r = 0; r < 4; ++r) {
                q0[r] = (_Float16)(acc[mi][2 * p][r]     + b0[r]);
                q1[r] = (_Float16)(acc[mi][2 * p + 1][r] + b1[r]);
            }
            *(f16x4*)&rec[(2 * p) * 256]     = q0;
            *(f16x4*)&rec[(2 * p + 1) * 256] = q1;
        }
    }
}

// ---------------------------------------------------------------------------
// Phase 2: persistent scan. 64 WGs x 4 waves (256 thr).
// group g = blk>>3 owns batch rows [16g,16g+16); slot w = blk&7 owns j-cols
// [64w,64w+64); wave wv owns j-tile [64w+16wv, +16), BOTH gates.
// Per step: poll 8 flags -> 32 u64 h atomic loads (full K) -> izlds ds_reads
// -> deferred H[t-1] store + izin(t+2) DMA (retire under compute; MFMA's h
// wait is vmcnt(2), not 0) -> 32 MFMA -> gates -> publish (1 u64/lane) ->
// vmcnt(0) -> syncthreads -> flag=t+2.
// Weights: 128KB LDS (wave wv: its 32 subtiles). izin: 4-slot x 4KB LDS ring.
// ---------------------------------------------------------------------------
__global__ __launch_bounds__(256, 1) void gru_scan(
    const _Float16* __restrict__ Whc,   // [1024][512] f16
    const char* izb,                    // d_out bytes: records (aliases Hout)
    float* Hout,                        // d_out as f32 [t][b][j]
    _Float16* hbuf,                     // [2][128][512] f16
    int* flags)                         // [8][8]
{
    __shared__ _Float16 wlds[65536];    // 128 KB: 128 subtiles x 1KB
    __shared__ _Float16 izlds[8192];    // 16 KB: 4 slots x 4KB

    const int blk = blockIdx.x;         // 0..63
    const int g = blk >> 3;
    const int w = blk & 7;
    const int tid = threadIdx.x;
    const int wv = tid >> 6;            // wave 0..3
    const int l = tid & 63;
    const int lrow = l & 15, lk = l >> 4;
    const int b = g * 16 + lrow;
    const int jq = w * 64 + wv * 16 + 4 * lk;   // lane's j quad base
    const int fi = g * 8 + (l & 7);

    // ---- stage weights: wave wv stages its 32 subtiles (2 gates x 16 s)
    for (int gate = 0; gate < 2; ++gate)
#pragma unroll
        for (int s = 0; s < 16; ++s) {
            const _Float16* gsrc = Whc +
                (size_t)(gate * 512 + w * 64 + wv * 16 + lrow) * 512 + s * 32 + lk * 8;
            gload_lds16(gsrc, &wlds[((wv * 2 + gate) * 16 + s) * 512]);
        }
    // ---- izin records 0,1: wave wv stages chunk wv (per-lane src!)
    {
        const char* r0 = izb + (size_t)blk * 4096 + wv * 1024 + (size_t)l * 16;
        gload_lds16(r0, &izlds[wv * 512]);
        const char* r1 = izb + (size_t)(64 + blk) * 4096 + wv * 1024 + (size_t)l * 16;
        gload_lds16(r1, &izlds[2048 + wv * 512]);
    }
    wait_vm0();
    __syncthreads();
    if (tid == 0)
        __hip_atomic_store(&flags[blk], 1, RLX, AGT);

    float hm[4] = {0.f, 0.f, 0.f, 0.f};   // h[b][jq+r] master (f32)
    f32x4 Hv = {0.f, 0.f, 0.f, 0.f};      // previous step's H values (deferred store)

    for (int t = 0; t < T_LEN; ++t) {
        // ---- group barrier: all 8 WGs of group g at phase >= t+1
        const int target = t + 1;
        while (true) {
            int v = __hip_atomic_load(&flags[fi], RLX, AGT);
            if (__all(v >= target)) break;
        }
        asm volatile("" ::: "memory");

        // ---- bulk h_t read (32 u64 relaxed agent atomics; full K per wave)
        const unsigned long long* hr = (const unsigned long long*)
            (hbuf + (size_t)((t + 1) & 1) * 65536 + (size_t)b * 512);
        U64x2 hh[16];
#pragma unroll
        for (int s = 0; s < 16; ++s) {
            hh[s].u[0] = __hip_atomic_load(hr + s * 8 + lk * 2,     RLX, AGT);
            hh[s].u[1] = __hip_atomic_load(hr + s * 8 + lk * 2 + 1, RLX, AGT);
        }

        // ---- izin for this step from LDS ring (before the DMA below!)
        const f16x4 zrec = *(const f16x4*)&izlds[(t & 3) * 2048 + wv * 256 + l * 4];
        const f16x4 nrec = *(const f16x4*)&izlds[(t & 3) * 2048 + 1024 + wv * 256 + l * 4];

        // ---- deferred H[t-1] store + izin(t+2) DMA: issued after the h loads
        //      so MFMA waits vmcnt(2) only; retire under compute.
        if (t)
            *(f32x4*)&Hout[(size_t)(t - 1) * 65536 + (size_t)b * 512 + jq] = Hv;
        if (t + 2 < T_LEN) {
            const char* src = izb + ((size_t)(t + 2) * 64 + blk) * 4096
                              + wv * 1024 + (size_t)l * 16;
            gload_lds16(src, &izlds[((t + 2) & 3) * 2048 + wv * 512]);
        }

        // ---- MFMA: 2 tiles (z, n) x 16 k-slices
        f32x4 az = {0.f, 0.f, 0.f, 0.f}, an = {0.f, 0.f, 0.f, 0.f};
#pragma unroll
        for (int s = 0; s < 16; ++s) {
            const f16x8 hv = hh[s].v;
            const f16x8 wz = *(const f16x8*)&wlds[((wv * 2 + 0) * 16 + s) * 512 + l * 8];
            const f16x8 wn = *(const f16x8*)&wlds[((wv * 2 + 1) * 16 + s) * 512 + l * 8];
            az = __builtin_amdgcn_mfma_f32_16x16x32_f16(wz, hv, az, 0, 0, 0);
            an = __builtin_amdgcn_mfma_f32_16x16x32_f16(wn, hv, an, 0, 0, 0);
        }

        // ---- gates + state update (f32)
        PK4 pk;
#pragma unroll
        for (int r = 0; r < 4; ++r) {
            float zpre = az[r] + (float)zrec[r];
            float npre = an[r] + (float)nrec[r];
            zpre = fminf(fmaxf(zpre, -30.f), 30.f);
            const float z = 1.f / (1.f + __expf(-zpre));
            npre = fminf(fmaxf(npre, -15.f), 15.f);
            const float e2 = __expf(2.f * npre);
            const float n = (e2 - 1.f) / (e2 + 1.f);
            hm[r] = (1.f - z) * n + z * hm[r];
            Hv[r] = hm[r];
            pk.h[r] = (_Float16)hm[r];
        }

        // ---- publish h_{t+1} (1 u64 write-through atomic per lane)
        __hip_atomic_store(
            (unsigned long long*)(hbuf + (size_t)(t & 1) * 65536 + (size_t)b * 512 + jq),
            pk.q, RLX, AGT);
        wait_vm0();          // drains publish (+H store/DMA long since retired)
        __syncthreads();     // all 4 waves drained
        if (tid == 0)
            __hip_atomic_store(&flags[blk], t + 2, RLX, AGT);
    }
    // final H[511] store
    *(f32x4*)&Hout[(size_t)(T_LEN - 1) * 65536 + (size_t)b * 512 + jq] = Hv;
}

// ---------------------------------------------------------------------------
extern "C" void kernel_launch(void* const* d_in, const int* in_sizes, int n_in,
                              void* d_out, int out_size, void* d_ws, size_t ws_size,
                              hipStream_t stream) {
    (void)in_sizes; (void)n_in; (void)out_size; (void)ws_size;
    const float* seq  = (const float*)d_in[0];
    const float* W_iz = (const float*)d_in[1];
    const float* b_iz = (const float*)d_in[2];
    const float* W_in = (const float*)d_in[3];
    const float* b_in = (const float*)d_in[4];
    const float* W_hz = (const float*)d_in[5];
    const float* b_hz = (const float*)d_in[6];
    const float* W_hn = (const float*)d_in[7];
    const float* b_hn = (const float*)d_in[8];

    char* ws = (char*)d_ws;                         // total use: ~2.4 MB
    _Float16* Wci   = (_Float16*)(ws);              // 1,048,576 B
    _Float16* Whc   = (_Float16*)(ws + 1048576);    // 1,048,576 B
    float*    bc    = (float*)   (ws + 2097152);    //     4,096 B
    _Float16* hbuf  = (_Float16*)(ws + 2101248);    //   262,144 B
    int*      flags = (int*)     (ws + 2363392);    //       256 B

    prep_misc<<<581, 256, 0, stream>>>(W_iz, W_in, W_hz, W_hn,
                                       b_iz, b_in, b_hz, b_hn,
                                       Wci, Whc, bc, hbuf, flags);
    gemm_proj<<<dim3(512, 8), 256, 0, stream>>>(seq, Wci, bc, (_Float16*)d_out);
    gru_scan<<<64, 256, 0, stream>>>(Whc, (const char*)d_out, (float*)d_out,
                                     hbuf, flags);
}